// Round 2
// baseline (4077.868 us; speedup 1.0000x reference)
//
#include <hip/hip_runtime.h>
#include <cstdint>
#include <cstddef>

#define NMAX 100000
#define EMAX 300000

// Static device scratch (zero-init .bss; fully rewritten every launch).
__device__ float    g_q   [(size_t)NMAX * 256];
__device__ float    g_k   [(size_t)NMAX * 256];
__device__ float    g_v   [(size_t)NMAX * 256];
__device__ float    g_e   [(size_t)EMAX * 256];
__device__ float    g_msg [(size_t)NMAX * 256];
__device__ float    g_ex  [(size_t)EMAX * 4];
__device__ unsigned g_amax[(size_t)NMAX * 4];
__device__ float    g_den [(size_t)NMAX * 4];

__device__ __forceinline__ unsigned fenc(float f) {
  unsigned u = __float_as_uint(f);
  return (u & 0x80000000u) ? ~u : (u | 0x80000000u);
}
__device__ __forceinline__ float fdec(unsigned u) {
  return (u & 0x80000000u) ? __uint_as_float(u & 0x7fffffffu) : __uint_as_float(~u);
}

// C[M,256] = A[M,K] @ W[K,256] + bias ; 64x64 tile, 256 threads, f32 SIMT.
template <int K>
__global__ __launch_bounds__(256) void gemm_bias(const float* __restrict__ A,
                                                 const float* __restrict__ W,
                                                 const float* __restrict__ bias,
                                                 float* __restrict__ C, int M) {
  __shared__ float sA[64][17];
  __shared__ float sW[16][64];
  const int bm = blockIdx.y * 64, bn = blockIdx.x * 64;
  const int tid = threadIdx.x;
  const int tx = tid & 15, ty = tid >> 4;
  const int arow = tid >> 2, acol = (tid & 3) << 2;
  const int wrow = tid >> 4, wcol = (tid & 15) << 2;
  const bool aok = (bm + arow) < M;
  const float* Ap = A + (long long)(bm + arow) * K + acol;
  const float* Wp = W + (long long)wrow * 256 + bn + wcol;
  float acc[4][4] = {};
  for (int k0 = 0; k0 < K; k0 += 16) {
    float4 av = aok ? *(const float4*)(Ap + k0) : make_float4(0.f, 0.f, 0.f, 0.f);
    float4 wv = *(const float4*)(Wp + (long long)k0 * 256);
    sA[arow][acol + 0] = av.x; sA[arow][acol + 1] = av.y;
    sA[arow][acol + 2] = av.z; sA[arow][acol + 3] = av.w;
    *(float4*)&sW[wrow][wcol] = wv;
    __syncthreads();
#pragma unroll
    for (int kk = 0; kk < 16; ++kk) {
      float4 w = *(const float4*)&sW[kk][tx << 2];
      float a0 = sA[(ty << 2) + 0][kk];
      float a1 = sA[(ty << 2) + 1][kk];
      float a2 = sA[(ty << 2) + 2][kk];
      float a3 = sA[(ty << 2) + 3][kk];
      acc[0][0] += a0 * w.x; acc[0][1] += a0 * w.y; acc[0][2] += a0 * w.z; acc[0][3] += a0 * w.w;
      acc[1][0] += a1 * w.x; acc[1][1] += a1 * w.y; acc[1][2] += a1 * w.z; acc[1][3] += a1 * w.w;
      acc[2][0] += a2 * w.x; acc[2][1] += a2 * w.y; acc[2][2] += a2 * w.z; acc[2][3] += a2 * w.w;
      acc[3][0] += a3 * w.x; acc[3][1] += a3 * w.y; acc[3][2] += a3 * w.z; acc[3][3] += a3 * w.w;
    }
    __syncthreads();
  }
  float4 bv = *(const float4*)(bias + bn + (tx << 2));
#pragma unroll
  for (int i = 0; i < 4; ++i) {
    int row = bm + (ty << 2) + i;
    if (row < M) {
      float4 r = make_float4(acc[i][0] + bv.x, acc[i][1] + bv.y,
                             acc[i][2] + bv.z, acc[i][3] + bv.w);
      *(float4*)(C + (long long)row * 256 + bn + (tx << 2)) = r;
    }
  }
}

// One wave per edge: logits[e][h] = SCALE * dot(q[dst][h], k[src][h]+e[e][h]); atomicMax.
__global__ __launch_bounds__(256) void edge_logits(const int* __restrict__ ei,
                                                   const float* __restrict__ q,
                                                   const float* __restrict__ k,
                                                   const float* __restrict__ e,
                                                   float* __restrict__ logit,
                                                   unsigned* __restrict__ amax, int E) {
  int eid = blockIdx.x * 4 + (threadIdx.x >> 6);
  if (eid >= E) return;
  int lane = threadIdx.x & 63;
  long long src = ei[eid], dst = ei[E + eid];
  int c4 = lane << 2;
  float4 qv = *(const float4*)(q + dst * 256 + c4);
  float4 kv = *(const float4*)(k + src * 256 + c4);
  float4 ev = *(const float4*)(e + (long long)eid * 256 + c4);
  float p = qv.x * (kv.x + ev.x) + qv.y * (kv.y + ev.y) +
            qv.z * (kv.z + ev.z) + qv.w * (kv.w + ev.w);
  p += __shfl_xor(p, 1); p += __shfl_xor(p, 2);
  p += __shfl_xor(p, 4); p += __shfl_xor(p, 8);
  if ((lane & 15) == 0) {
    int h = lane >> 4;
    float lg = p * 0.125f;
    logit[(long long)eid * 4 + h] = lg;
    atomicMax(&amax[dst * 4 + h], fenc(lg));
  }
}

// One thread per (edge,head): ex = exp(logit - amax[dst]); denom += ex.
__global__ __launch_bounds__(256) void edge_exp(const int* __restrict__ ei,
                                                float* __restrict__ logit,
                                                const unsigned* __restrict__ amax,
                                                float* __restrict__ denom, int E) {
  int i = blockIdx.x * 256 + threadIdx.x;
  if (i >= E * 4) return;
  int eid = i >> 2, h = i & 3;
  long long dst = ei[E + eid];
  float m = fdec(amax[dst * 4 + h]);
  float ex = expf(logit[i] - m);
  logit[i] = ex;
  atomicAdd(&denom[dst * 4 + h], ex);
}

// One wave per edge: msg[dst] += alpha * (v[src] + e).
__global__ __launch_bounds__(256) void edge_agg(const int* __restrict__ ei,
                                                const float* __restrict__ exv,
                                                const float* __restrict__ denom,
                                                const float* __restrict__ v,
                                                const float* __restrict__ e,
                                                float* __restrict__ msg, int E) {
  int eid = blockIdx.x * 4 + (threadIdx.x >> 6);
  if (eid >= E) return;
  int lane = threadIdx.x & 63;
  long long src = ei[eid], dst = ei[E + eid];
  int h = lane >> 4;
  float alpha = exv[(long long)eid * 4 + h] / denom[dst * 4 + h];
  int c4 = lane << 2;
  float4 vv = *(const float4*)(v + src * 256 + c4);
  float4 ev = *(const float4*)(e + (long long)eid * 256 + c4);
  float* m = msg + dst * 256 + c4;
  atomicAdd(m + 0, alpha * (vv.x + ev.x));
  atomicAdd(m + 1, alpha * (vv.y + ev.y));
  atomicAdd(m + 2, alpha * (vv.z + ev.z));
  atomicAdd(m + 3, alpha * (vv.w + ev.w));
}

__device__ __forceinline__ float waveReduceSum(float v) {
#pragma unroll
  for (int o = 1; o < 64; o <<= 1) v += __shfl_xor(v, o);
  return v;
}

// out = LN(x + msg) * gamma + beta ; one block (256 thr) per row, D=256.
__global__ __launch_bounds__(256) void ln_kernel(const float* __restrict__ x,
                                                 const float* __restrict__ msg,
                                                 const float* __restrict__ gamma,
                                                 const float* __restrict__ beta,
                                                 float* __restrict__ out) {
  int r = blockIdx.x;
  int c = threadIdx.x;
  long long base = (long long)r * 256;
  float val = x[base + c] + msg[base + c];
  __shared__ float sred[4];
  int wid = c >> 6, lane = c & 63;
  float s = waveReduceSum(val);
  if (!lane) sred[wid] = s;
  __syncthreads();
  float m = (sred[0] + sred[1] + sred[2] + sred[3]) * (1.0f / 256.0f);
  float d = val - m;
  __syncthreads();
  s = waveReduceSum(d * d);
  if (!lane) sred[wid] = s;
  __syncthreads();
  float var = (sred[0] + sred[1] + sred[2] + sred[3]) * (1.0f / 256.0f);
  out[base + c] = d * rsqrtf(var + 1e-5f) * gamma[c] + beta[c];
}

extern "C" void kernel_launch(void* const* d_in, const int* in_sizes, int n_in,
                              void* d_out, int out_size, void* d_ws, size_t ws_size,
                              hipStream_t stream) {
  const float* row_x   = (const float*)d_in[0];
  const float* token_x = (const float*)d_in[1];
  const int*   ei1     = (const int*)d_in[2];    // int32! (JAX x64 disabled)
  const float* ea1     = (const float*)d_in[3];
  const int*   ei2     = (const int*)d_in[4];
  const float* ea2     = (const float*)d_in[5];

  // t2r: 6..15  (Wq,bq,Wk,bk,Wv,bv,We,be,Ws,bs) ; r2t: 16..25
  const float* W1q = (const float*)d_in[6];  const float* b1q = (const float*)d_in[7];
  const float* W1k = (const float*)d_in[8];  const float* b1k = (const float*)d_in[9];
  const float* W1v = (const float*)d_in[10]; const float* b1v = (const float*)d_in[11];
  const float* W1e = (const float*)d_in[12]; const float* b1e = (const float*)d_in[13];
  const float* W1s = (const float*)d_in[14]; const float* b1s = (const float*)d_in[15];
  const float* W2q = (const float*)d_in[16]; const float* b2q = (const float*)d_in[17];
  const float* W2k = (const float*)d_in[18]; const float* b2k = (const float*)d_in[19];
  const float* W2v = (const float*)d_in[20]; const float* b2v = (const float*)d_in[21];
  const float* W2e = (const float*)d_in[22]; const float* b2e = (const float*)d_in[23];
  const float* W2s = (const float*)d_in[24]; const float* b2s = (const float*)d_in[25];
  const float* row_gamma   = (const float*)d_in[26];
  const float* row_beta    = (const float*)d_in[27];
  const float* token_gamma = (const float*)d_in[28];
  const float* token_beta  = (const float*)d_in[29];

  const int NR = in_sizes[0] / 256;   // 20000
  const int NT = in_sizes[1] / 256;   // 100000
  const int E  = in_sizes[2] / 2;     // 300000

  float* out_row = (float*)d_out;
  float* out_tok = (float*)d_out + (long long)NR * 256;

  void *pq_, *pk_, *pv_, *pe_, *pmsg_, *pex_, *pamax_, *pden_;
  hipGetSymbolAddress(&pq_,   HIP_SYMBOL(g_q));
  hipGetSymbolAddress(&pk_,   HIP_SYMBOL(g_k));
  hipGetSymbolAddress(&pv_,   HIP_SYMBOL(g_v));
  hipGetSymbolAddress(&pe_,   HIP_SYMBOL(g_e));
  hipGetSymbolAddress(&pmsg_, HIP_SYMBOL(g_msg));
  hipGetSymbolAddress(&pex_,  HIP_SYMBOL(g_ex));
  hipGetSymbolAddress(&pamax_,HIP_SYMBOL(g_amax));
  hipGetSymbolAddress(&pden_, HIP_SYMBOL(g_den));
  float*    q    = (float*)pq_;
  float*    k    = (float*)pk_;
  float*    v    = (float*)pv_;
  float*    e    = (float*)pe_;
  float*    msg  = (float*)pmsg_;
  float*    ex   = (float*)pex_;
  unsigned* amax = (unsigned*)pamax_;
  float*    den  = (float*)pden_;

  auto g256 = [&](const float* A, const float* W, const float* b, float* C, int M) {
    dim3 grid(4, (M + 63) / 64);
    gemm_bias<256><<<grid, 256, 0, stream>>>(A, W, b, C, M);
  };
  auto g128 = [&](const float* A, const float* W, const float* b, float* C, int M) {
    dim3 grid(4, (M + 63) / 64);
    gemm_bias<128><<<grid, 256, 0, stream>>>(A, W, b, C, M);
  };

  const int egrid  = (E + 3) / 4;
  const int ehgrid = (E * 4 + 255) / 256;

  // ---------------- Phase 1: t2r (tokens -> rows) ----------------
  g256(row_x,   W1q, b1q, q,   NR);
  g256(token_x, W1k, b1k, k,   NT);
  g256(token_x, W1v, b1v, v,   NT);
  g128(ea1,     W1e, b1e, e,   E);
  g256(row_x,   W1s, b1s, msg, NR);   // skip-linear seeds msg accumulator
  hipMemsetAsync(amax, 0, (size_t)NR * 4 * sizeof(unsigned), stream);
  hipMemsetAsync(den,  0, (size_t)NR * 4 * sizeof(float),    stream);
  edge_logits<<<egrid, 256, 0, stream>>>(ei1, q, k, e, ex, amax, E);
  edge_exp   <<<ehgrid, 256, 0, stream>>>(ei1, ex, amax, den, E);
  edge_agg   <<<egrid, 256, 0, stream>>>(ei1, ex, den, v, e, msg, E);
  ln_kernel  <<<NR, 256, 0, stream>>>(row_x, msg, row_gamma, row_beta, out_row);

  // ---------------- Phase 2: r2t (rows -> tokens) ----------------
  g256(token_x, W2q, b2q, q,   NT);
  g256(out_row, W2k, b2k, k,   NR);
  g256(out_row, W2v, b2v, v,   NR);
  g128(ea2,     W2e, b2e, e,   E);
  g256(token_x, W2s, b2s, msg, NT);
  hipMemsetAsync(amax, 0, (size_t)NT * 4 * sizeof(unsigned), stream);
  hipMemsetAsync(den,  0, (size_t)NT * 4 * sizeof(float),    stream);
  edge_logits<<<egrid, 256, 0, stream>>>(ei2, q, k, e, ex, amax, E);
  edge_exp   <<<ehgrid, 256, 0, stream>>>(ei2, ex, amax, den, E);
  edge_agg   <<<egrid, 256, 0, stream>>>(ei2, ex, den, v, e, msg, E);
  ln_kernel  <<<NT, 256, 0, stream>>>(token_x, msg, token_gamma, token_beta, out_tok);
}

// Round 3
// 1931.039 us; speedup vs baseline: 2.1117x; 2.1117x over previous
//
#include <hip/hip_runtime.h>
#include <cstdint>
#include <cstddef>

#define NMAX 100000
#define EMAX 300000

// Static device scratch (fully rewritten every launch).
__device__ float g_q   [(size_t)NMAX * 256];
__device__ float g_k   [(size_t)NMAX * 256];
__device__ float g_v   [(size_t)NMAX * 256];
__device__ float g_e   [(size_t)EMAX * 256];
__device__ float g_s   [(size_t)NMAX * 256];
__device__ int   g_deg [NMAX + 1];
__device__ int   g_rowptr[NMAX + 1];
__device__ int   g_cur [NMAX];
__device__ int   g_perm[EMAX];
__device__ int   g_bsum[512];

// C[M,256] = A[M,K] @ W[K,256] + bias ; 64x64 tile, 256 threads, f32 SIMT.
template <int K>
__global__ __launch_bounds__(256) void gemm_bias(const float* __restrict__ A,
                                                 const float* __restrict__ W,
                                                 const float* __restrict__ bias,
                                                 float* __restrict__ C, int M) {
  __shared__ float sA[64][17];
  __shared__ float sW[16][64];
  const int bm = blockIdx.y * 64, bn = blockIdx.x * 64;
  const int tid = threadIdx.x;
  const int tx = tid & 15, ty = tid >> 4;
  const int arow = tid >> 2, acol = (tid & 3) << 2;
  const int wrow = tid >> 4, wcol = (tid & 15) << 2;
  const bool aok = (bm + arow) < M;
  const float* Ap = A + (long long)(bm + arow) * K + acol;
  const float* Wp = W + (long long)wrow * 256 + bn + wcol;
  float acc[4][4] = {};
  for (int k0 = 0; k0 < K; k0 += 16) {
    float4 av = aok ? *(const float4*)(Ap + k0) : make_float4(0.f, 0.f, 0.f, 0.f);
    float4 wv = *(const float4*)(Wp + (long long)k0 * 256);
    sA[arow][acol + 0] = av.x; sA[arow][acol + 1] = av.y;
    sA[arow][acol + 2] = av.z; sA[arow][acol + 3] = av.w;
    *(float4*)&sW[wrow][wcol] = wv;
    __syncthreads();
#pragma unroll
    for (int kk = 0; kk < 16; ++kk) {
      float4 w = *(const float4*)&sW[kk][tx << 2];
      float a0 = sA[(ty << 2) + 0][kk];
      float a1 = sA[(ty << 2) + 1][kk];
      float a2 = sA[(ty << 2) + 2][kk];
      float a3 = sA[(ty << 2) + 3][kk];
      acc[0][0] += a0 * w.x; acc[0][1] += a0 * w.y; acc[0][2] += a0 * w.z; acc[0][3] += a0 * w.w;
      acc[1][0] += a1 * w.x; acc[1][1] += a1 * w.y; acc[1][2] += a1 * w.z; acc[1][3] += a1 * w.w;
      acc[2][0] += a2 * w.x; acc[2][1] += a2 * w.y; acc[2][2] += a2 * w.z; acc[2][3] += a2 * w.w;
      acc[3][0] += a3 * w.x; acc[3][1] += a3 * w.y; acc[3][2] += a3 * w.z; acc[3][3] += a3 * w.w;
    }
    __syncthreads();
  }
  float4 bv = *(const float4*)(bias + bn + (tx << 2));
#pragma unroll
  for (int i = 0; i < 4; ++i) {
    int row = bm + (ty << 2) + i;
    if (row < M) {
      float4 r = make_float4(acc[i][0] + bv.x, acc[i][1] + bv.y,
                             acc[i][2] + bv.z, acc[i][3] + bv.w);
      *(float4*)(C + (long long)row * 256 + bn + (tx << 2)) = r;
    }
  }
}

// ---------------- CSR build ----------------
__global__ __launch_bounds__(256) void hist_kernel(const int* __restrict__ ei,
                                                   int* __restrict__ deg, int E) {
  int i = blockIdx.x * 256 + threadIdx.x;
  if (i < E) atomicAdd(&deg[ei[E + i]], 1);
}

// Per-256 block exclusive scan; block totals to bsum.
__global__ __launch_bounds__(256) void scan1(const int* __restrict__ deg,
                                             int* __restrict__ rowptr,
                                             int* __restrict__ bsum, int n) {
  __shared__ int ws[4];
  int i = blockIdx.x * 256 + threadIdx.x;
  int v = (i < n) ? deg[i] : 0;
  int lane = threadIdx.x & 63, wid = threadIdx.x >> 6;
  int inc = v;
#pragma unroll
  for (int o = 1; o < 64; o <<= 1) {
    int t = __shfl_up(inc, o);
    if (lane >= o) inc += t;
  }
  if (lane == 63) ws[wid] = inc;
  __syncthreads();
  int woff = 0;
  if (wid > 0) woff += ws[0];
  if (wid > 1) woff += ws[1];
  if (wid > 2) woff += ws[2];
  if (i < n) rowptr[i] = inc - v + woff;
  if (threadIdx.x == 255) bsum[blockIdx.x] = inc + woff;
}

// Single-block exclusive scan of block sums (B <= 512).
__global__ __launch_bounds__(512) void scan2(int* __restrict__ bsum, int B) {
  __shared__ int s[512];
  int t = threadIdx.x;
  int v = (t < B) ? bsum[t] : 0;
  s[t] = v;
  __syncthreads();
  for (int o = 1; o < 512; o <<= 1) {
    int a = (t >= o) ? s[t - o] : 0;
    __syncthreads();
    s[t] += a;
    __syncthreads();
  }
  if (t < B) bsum[t] = s[t] - v;
}

__global__ __launch_bounds__(256) void scan3(int* __restrict__ rowptr,
                                             const int* __restrict__ bsum,
                                             const int* __restrict__ deg,
                                             int* __restrict__ cur, int n) {
  int i = blockIdx.x * 256 + threadIdx.x;
  if (i < n) {
    int r = rowptr[i] + bsum[blockIdx.x];
    rowptr[i] = r;
    cur[i] = r;
    if (i == n - 1) rowptr[n] = r + deg[i];
  }
}

__global__ __launch_bounds__(256) void scatter_kernel(const int* __restrict__ ei,
                                                      int* __restrict__ cur,
                                                      int* __restrict__ perm, int E) {
  int i = blockIdx.x * 256 + threadIdx.x;
  if (i < E) {
    int d = ei[E + i];
    int pos = atomicAdd(&cur[d], 1);
    perm[pos] = i;
  }
}

// ---------------- Fused attention + skip + residual + LN ----------------
// One wave per dst node; lane owns 4 channels (col = 4*lane .. 4*lane+3),
// 16-lane groups = heads. Flash-style online softmax; zero atomics.
__global__ __launch_bounds__(256) void fused_attn_ln(
    const int* __restrict__ ei, const int* __restrict__ rowptr,
    const int* __restrict__ perm,
    const float* __restrict__ q, const float* __restrict__ k,
    const float* __restrict__ v, const float* __restrict__ e,
    const float* __restrict__ x, const float* __restrict__ s,
    const float* __restrict__ gamma, const float* __restrict__ beta,
    float* __restrict__ out, int N, int E) {
  int node = blockIdx.x * 4 + (threadIdx.x >> 6);
  if (node >= N) return;
  int lane = threadIdx.x & 63;
  int c4 = lane << 2;
  long long base = (long long)node * 256 + c4;
  float4 qv = *(const float4*)(q + base);
  float4 acc = make_float4(0.f, 0.f, 0.f, 0.f);
  float m = -1e30f, den = 0.f;
  int beg = rowptr[node], end = rowptr[node + 1];
  for (int p_ = beg; p_ < end; ++p_) {
    int eid = perm[p_];
    long long src = ei[eid];
    float4 kv = *(const float4*)(k + src * 256 + c4);
    float4 ev = *(const float4*)(e + (long long)eid * 256 + c4);
    float4 vv = *(const float4*)(v + src * 256 + c4);
    float p = qv.x * (kv.x + ev.x) + qv.y * (kv.y + ev.y) +
              qv.z * (kv.z + ev.z) + qv.w * (kv.w + ev.w);
    p += __shfl_xor(p, 1); p += __shfl_xor(p, 2);
    p += __shfl_xor(p, 4); p += __shfl_xor(p, 8);
    p *= 0.125f;                      // SCALE = 1/sqrt(64)
    float mn = fmaxf(m, p);
    float sc = expf(m - mn);          // 0 on first edge (m=-1e30)
    float w  = expf(p - mn);
    den = den * sc + w;
    acc.x = acc.x * sc + w * (vv.x + ev.x);
    acc.y = acc.y * sc + w * (vv.y + ev.y);
    acc.z = acc.z * sc + w * (vv.z + ev.z);
    acc.w = acc.w * sc + w * (vv.w + ev.w);
    m = mn;
  }
  float inv = (den > 0.f) ? 1.0f / den : 0.f;
  float4 sv = *(const float4*)(s + base);
  float4 xv = *(const float4*)(x + base);
  float4 val = make_float4(xv.x + sv.x + acc.x * inv,
                           xv.y + sv.y + acc.y * inv,
                           xv.z + sv.z + acc.z * inv,
                           xv.w + sv.w + acc.w * inv);
  // LayerNorm over the 256-wide row (64 lanes x 4 channels), wave-only.
  float t = val.x + val.y + val.z + val.w;
#pragma unroll
  for (int o = 1; o < 64; o <<= 1) t += __shfl_xor(t, o);
  float mean = t * (1.0f / 256.0f);
  float d0 = val.x - mean, d1 = val.y - mean, d2 = val.z - mean, d3 = val.w - mean;
  float ss = d0 * d0 + d1 * d1 + d2 * d2 + d3 * d3;
#pragma unroll
  for (int o = 1; o < 64; o <<= 1) ss += __shfl_xor(ss, o);
  float rstd = rsqrtf(ss * (1.0f / 256.0f) + 1e-5f);
  float4 gv = *(const float4*)(gamma + c4);
  float4 bv = *(const float4*)(beta + c4);
  float4 o4 = make_float4(d0 * rstd * gv.x + bv.x, d1 * rstd * gv.y + bv.y,
                          d2 * rstd * gv.z + bv.z, d3 * rstd * gv.w + bv.w);
  *(float4*)(out + base) = o4;
}

extern "C" void kernel_launch(void* const* d_in, const int* in_sizes, int n_in,
                              void* d_out, int out_size, void* d_ws, size_t ws_size,
                              hipStream_t stream) {
  const float* row_x   = (const float*)d_in[0];
  const float* token_x = (const float*)d_in[1];
  const int*   ei1     = (const int*)d_in[2];    // int32 (JAX x64 disabled)
  const float* ea1     = (const float*)d_in[3];
  const int*   ei2     = (const int*)d_in[4];
  const float* ea2     = (const float*)d_in[5];

  const float* W1q = (const float*)d_in[6];  const float* b1q = (const float*)d_in[7];
  const float* W1k = (const float*)d_in[8];  const float* b1k = (const float*)d_in[9];
  const float* W1v = (const float*)d_in[10]; const float* b1v = (const float*)d_in[11];
  const float* W1e = (const float*)d_in[12]; const float* b1e = (const float*)d_in[13];
  const float* W1s = (const float*)d_in[14]; const float* b1s = (const float*)d_in[15];
  const float* W2q = (const float*)d_in[16]; const float* b2q = (const float*)d_in[17];
  const float* W2k = (const float*)d_in[18]; const float* b2k = (const float*)d_in[19];
  const float* W2v = (const float*)d_in[20]; const float* b2v = (const float*)d_in[21];
  const float* W2e = (const float*)d_in[22]; const float* b2e = (const float*)d_in[23];
  const float* W2s = (const float*)d_in[24]; const float* b2s = (const float*)d_in[25];
  const float* row_gamma   = (const float*)d_in[26];
  const float* row_beta    = (const float*)d_in[27];
  const float* token_gamma = (const float*)d_in[28];
  const float* token_beta  = (const float*)d_in[29];

  const int NR = in_sizes[0] / 256;   // 20000
  const int NT = in_sizes[1] / 256;   // 100000
  const int E  = in_sizes[2] / 2;     // 300000

  float* out_row = (float*)d_out;
  float* out_tok = (float*)d_out + (long long)NR * 256;

  void *pq_, *pk_, *pv_, *pe_, *ps_, *pdeg_, *prp_, *pcur_, *pperm_, *pbs_;
  hipGetSymbolAddress(&pq_,   HIP_SYMBOL(g_q));
  hipGetSymbolAddress(&pk_,   HIP_SYMBOL(g_k));
  hipGetSymbolAddress(&pv_,   HIP_SYMBOL(g_v));
  hipGetSymbolAddress(&pe_,   HIP_SYMBOL(g_e));
  hipGetSymbolAddress(&ps_,   HIP_SYMBOL(g_s));
  hipGetSymbolAddress(&pdeg_, HIP_SYMBOL(g_deg));
  hipGetSymbolAddress(&prp_,  HIP_SYMBOL(g_rowptr));
  hipGetSymbolAddress(&pcur_, HIP_SYMBOL(g_cur));
  hipGetSymbolAddress(&pperm_,HIP_SYMBOL(g_perm));
  hipGetSymbolAddress(&pbs_,  HIP_SYMBOL(g_bsum));
  float* q    = (float*)pq_;
  float* k    = (float*)pk_;
  float* v    = (float*)pv_;
  float* e    = (float*)pe_;
  float* s    = (float*)ps_;
  int*   deg  = (int*)pdeg_;
  int*   rp   = (int*)prp_;
  int*   cur  = (int*)pcur_;
  int*   perm = (int*)pperm_;
  int*   bsum = (int*)pbs_;

  auto g256 = [&](const float* A, const float* W, const float* b, float* C, int M) {
    dim3 grid(4, (M + 63) / 64);
    gemm_bias<256><<<grid, 256, 0, stream>>>(A, W, b, C, M);
  };
  auto g128 = [&](const float* A, const float* W, const float* b, float* C, int M) {
    dim3 grid(4, (M + 63) / 64);
    gemm_bias<128><<<grid, 256, 0, stream>>>(A, W, b, C, M);
  };

  const int egrid = (E + 255) / 256;

  auto run_phase = [&](const float* x_src, const float* x_dst, const int* ei,
                       const float* ea,
                       const float* Wq, const float* bq, const float* Wk, const float* bk,
                       const float* Wv, const float* bv, const float* We, const float* be,
                       const float* Ws, const float* bs,
                       const float* gamma, const float* beta,
                       float* outp, int Ndst, int Nsrc) {
    g256(x_dst, Wq, bq, q, Ndst);
    g256(x_src, Wk, bk, k, Nsrc);
    g256(x_src, Wv, bv, v, Nsrc);
    g128(ea,    We, be, e, E);
    g256(x_dst, Ws, bs, s, Ndst);
    // CSR build over dst
    hipMemsetAsync(deg, 0, (size_t)(Ndst + 1) * sizeof(int), stream);
    hist_kernel<<<egrid, 256, 0, stream>>>(ei, deg, E);
    int B = (Ndst + 255) / 256;
    scan1<<<B, 256, 0, stream>>>(deg, rp, bsum, Ndst);
    scan2<<<1, 512, 0, stream>>>(bsum, B);
    scan3<<<B, 256, 0, stream>>>(rp, bsum, deg, cur, Ndst);
    scatter_kernel<<<egrid, 256, 0, stream>>>(ei, cur, perm, E);
    // Fused attention + LN
    fused_attn_ln<<<(Ndst + 3) / 4, 256, 0, stream>>>(ei, rp, perm, q, k, v, e,
                                                      x_dst, s, gamma, beta,
                                                      outp, Ndst, E);
  };

  // Phase 1: t2r (tokens -> rows)
  run_phase(token_x, row_x, ei1, ea1,
            W1q, b1q, W1k, b1k, W1v, b1v, W1e, b1e, W1s, b1s,
            row_gamma, row_beta, out_row, NR, NT);
  // Phase 2: r2t (rows -> tokens), K/V from row_out
  run_phase(out_row, token_x, ei2, ea2,
            W2q, b2q, W2k, b2k, W2v, b2v, W2e, b2e, W2s, b2s,
            token_gamma, token_beta, out_tok, NT, NR);
}

// Round 4
// 1490.451 us; speedup vs baseline: 2.7360x; 1.2956x over previous
//
#include <hip/hip_runtime.h>
#include <cstdint>
#include <cstddef>

#define NMAX 100000
#define EMAX 300000

typedef __bf16 bf16x8 __attribute__((ext_vector_type(8)));
typedef float f32x4 __attribute__((ext_vector_type(4)));

// Static device scratch (fully rewritten every launch).
__device__ float g_q   [(size_t)NMAX * 256];
__device__ float g_k   [(size_t)NMAX * 256];
__device__ float g_v   [(size_t)NMAX * 256];
__device__ float g_e   [(size_t)EMAX * 256];
__device__ float g_s   [(size_t)NMAX * 256];
__device__ unsigned short g_bfA[(size_t)NMAX * 256];   // token_x bf16 (both phases)
__device__ unsigned short g_bfB[(size_t)NMAX * 256];   // row_x bf16 (ph1) / out_row bf16 (ph2)
__device__ unsigned short g_bfE[(size_t)EMAX * 128];   // edge_attr bf16 (per phase)
__device__ unsigned short g_bfW[(size_t)10 * 256 * 256]; // transposed bf16 weights
__device__ int   g_deg [NMAX + 1];
__device__ int   g_rowptr[NMAX + 1];
__device__ int   g_cur [NMAX];
__device__ int   g_perm[EMAX];
__device__ int   g_bsum[512];

__device__ __forceinline__ unsigned short f2bf(float f) {
  unsigned u = __float_as_uint(f);
  return (unsigned short)((u + 0x7fffu + ((u >> 16) & 1u)) >> 16);
}

// f32 -> bf16, 8 elems/thread (n must be multiple of 8).
__global__ __launch_bounds__(256) void conv_bf16(const float* __restrict__ in,
                                                 unsigned short* __restrict__ out,
                                                 long long n8) {
  long long i = (long long)blockIdx.x * 256 + threadIdx.x;
  if (i >= n8) return;
  const float4* p = (const float4*)(in + i * 8);
  float4 a = p[0], b = p[1];
  ushort4 lo = make_ushort4(f2bf(a.x), f2bf(a.y), f2bf(a.z), f2bf(a.w));
  ushort4 hi = make_ushort4(f2bf(b.x), f2bf(b.y), f2bf(b.z), f2bf(b.w));
  ushort4* q = (ushort4*)(out + i * 8);
  q[0] = lo; q[1] = hi;
}

// W[K,256] f32 -> Wt[256,K] bf16 (transpose-convert).
__global__ __launch_bounds__(256) void wconv(const float* __restrict__ W,
                                             unsigned short* __restrict__ Wt, int K) {
  int i = blockIdx.x * 256 + threadIdx.x;
  if (i < K * 256) {
    int k = i >> 8, n = i & 255;
    Wt[(size_t)n * K + k] = f2bf(W[i]);
  }
}

#define GLL16(gp, lp) __builtin_amdgcn_global_load_lds( \
    (const __attribute__((address_space(1))) void*)(gp), \
    (__attribute__((address_space(3))) void*)(lp), 16, 0, 0)

// C[M,256] = bf16(A[M,K]) @ bf16(W[K,256]) + bias, f32 out.
// 128x128 tile, BK=64, 4 waves (2x2), 16x16x32 bf16 MFMA, global_load_lds
// staging with XOR swizzle (slot ^= row&7) on both source and ds_read side.
template <int K>
__global__ __launch_bounds__(256) void gemm_mfma(const unsigned short* __restrict__ A,
                                                 const unsigned short* __restrict__ Bt,
                                                 const float* __restrict__ bias,
                                                 float* __restrict__ C, int M) {
  __shared__ unsigned short As[128 * 64];
  __shared__ unsigned short Bs[128 * 64];
  const int tid = threadIdx.x;
  const int lane = tid & 63, wid = tid >> 6;
  const int bm = blockIdx.x * 128, bn = blockIdx.y * 128;
  const int wrow = (wid & 1) * 64, wcol = (wid >> 1) * 64;
  const int sr = lane >> 3;     // staging sub-row 0..7
  const int slot = lane & 7;    // staging 16B slot 0..7

  f32x4 acc[4][4] = {};

  for (int k0 = 0; k0 < K; k0 += 64) {
#pragma unroll
    for (int r = 0; r < 4; ++r) {
      int row = (wid * 4 + r) * 8 + sr;            // 0..127
      int arow = bm + row; if (arow >= M) arow = M - 1;
      int kk = k0 + ((slot ^ (row & 7)) << 3);
      GLL16(A + (size_t)arow * K + kk, (unsigned short*)As + (size_t)(wid * 4 + r) * 512);
    }
#pragma unroll
    for (int r = 0; r < 4; ++r) {
      int col = (wid * 4 + r) * 8 + sr;            // 0..127 (col of C / row of Bt)
      int kk = k0 + ((slot ^ (col & 7)) << 3);
      GLL16(Bt + (size_t)(bn + col) * K + kk, (unsigned short*)Bs + (size_t)(wid * 4 + r) * 512);
    }
    __syncthreads();
    const char* Ab = (const char*)As;
    const char* Bb = (const char*)Bs;
#pragma unroll
    for (int h = 0; h < 2; ++h) {
      bf16x8 af[4], bfr[4];
      int g = (lane >> 4) + h * 4;                 // k-group 0..7
#pragma unroll
      for (int fm = 0; fm < 4; ++fm) {
        int row = wrow + fm * 16 + (lane & 15);
        af[fm] = *(const bf16x8*)(Ab + row * 128 + ((g ^ (row & 7)) << 4));
      }
#pragma unroll
      for (int fn = 0; fn < 4; ++fn) {
        int col = wcol + fn * 16 + (lane & 15);
        bfr[fn] = *(const bf16x8*)(Bb + col * 128 + ((g ^ (col & 7)) << 4));
      }
#pragma unroll
      for (int fm = 0; fm < 4; ++fm)
#pragma unroll
        for (int fn = 0; fn < 4; ++fn)
          acc[fm][fn] = __builtin_amdgcn_mfma_f32_16x16x32_bf16(af[fm], bfr[fn],
                                                                acc[fm][fn], 0, 0, 0);
    }
    __syncthreads();
  }
#pragma unroll
  for (int fn = 0; fn < 4; ++fn) {
    int col = bn + wcol + fn * 16 + (lane & 15);
    float bv = bias[col];
#pragma unroll
    for (int fm = 0; fm < 4; ++fm) {
      int rbase = bm + wrow + fm * 16 + ((lane >> 4) << 2);
#pragma unroll
      for (int j = 0; j < 4; ++j) {
        int row = rbase + j;
        if (row < M) C[(size_t)row * 256 + col] = acc[fm][fn][j] + bv;
      }
    }
  }
}

// ---------------- CSR build ----------------
__global__ __launch_bounds__(256) void hist_kernel(const int* __restrict__ ei,
                                                   int* __restrict__ deg, int E) {
  int i = blockIdx.x * 256 + threadIdx.x;
  if (i < E) atomicAdd(&deg[ei[E + i]], 1);
}

__global__ __launch_bounds__(256) void scan1(const int* __restrict__ deg,
                                             int* __restrict__ rowptr,
                                             int* __restrict__ bsum, int n) {
  __shared__ int ws[4];
  int i = blockIdx.x * 256 + threadIdx.x;
  int v = (i < n) ? deg[i] : 0;
  int lane = threadIdx.x & 63, wid = threadIdx.x >> 6;
  int inc = v;
#pragma unroll
  for (int o = 1; o < 64; o <<= 1) {
    int t = __shfl_up(inc, o);
    if (lane >= o) inc += t;
  }
  if (lane == 63) ws[wid] = inc;
  __syncthreads();
  int woff = 0;
  if (wid > 0) woff += ws[0];
  if (wid > 1) woff += ws[1];
  if (wid > 2) woff += ws[2];
  if (i < n) rowptr[i] = inc - v + woff;
  if (threadIdx.x == 255) bsum[blockIdx.x] = inc + woff;
}

__global__ __launch_bounds__(512) void scan2(int* __restrict__ bsum, int B) {
  __shared__ int s[512];
  int t = threadIdx.x;
  int v = (t < B) ? bsum[t] : 0;
  s[t] = v;
  __syncthreads();
  for (int o = 1; o < 512; o <<= 1) {
    int a = (t >= o) ? s[t - o] : 0;
    __syncthreads();
    s[t] += a;
    __syncthreads();
  }
  if (t < B) bsum[t] = s[t] - v;
}

__global__ __launch_bounds__(256) void scan3(int* __restrict__ rowptr,
                                             const int* __restrict__ bsum,
                                             const int* __restrict__ deg,
                                             int* __restrict__ cur, int n) {
  int i = blockIdx.x * 256 + threadIdx.x;
  if (i < n) {
    int r = rowptr[i] + bsum[blockIdx.x];
    rowptr[i] = r;
    cur[i] = r;
    if (i == n - 1) rowptr[n] = r + deg[i];
  }
}

__global__ __launch_bounds__(256) void scatter_kernel(const int* __restrict__ ei,
                                                      int* __restrict__ cur,
                                                      int* __restrict__ perm, int E) {
  int i = blockIdx.x * 256 + threadIdx.x;
  if (i < E) {
    int d = ei[E + i];
    int pos = atomicAdd(&cur[d], 1);
    perm[pos] = i;
  }
}

// ---------------- Fused attention + skip + residual + LN ----------------
__global__ __launch_bounds__(256) void fused_attn_ln(
    const int* __restrict__ ei, const int* __restrict__ rowptr,
    const int* __restrict__ perm,
    const float* __restrict__ q, const float* __restrict__ k,
    const float* __restrict__ v, const float* __restrict__ e,
    const float* __restrict__ x, const float* __restrict__ s,
    const float* __restrict__ gamma, const float* __restrict__ beta,
    float* __restrict__ out, int N, int E) {
  int node = blockIdx.x * 4 + (threadIdx.x >> 6);
  if (node >= N) return;
  int lane = threadIdx.x & 63;
  int c4 = lane << 2;
  long long base = (long long)node * 256 + c4;
  float4 qv = *(const float4*)(q + base);
  float4 acc = make_float4(0.f, 0.f, 0.f, 0.f);
  float m = -1e30f, den = 0.f;
  int beg = rowptr[node], end = rowptr[node + 1];
  for (int p_ = beg; p_ < end; ++p_) {
    int eid = perm[p_];
    long long src = ei[eid];
    float4 kv = *(const float4*)(k + src * 256 + c4);
    float4 ev = *(const float4*)(e + (long long)eid * 256 + c4);
    float4 vv = *(const float4*)(v + src * 256 + c4);
    float p = qv.x * (kv.x + ev.x) + qv.y * (kv.y + ev.y) +
              qv.z * (kv.z + ev.z) + qv.w * (kv.w + ev.w);
    p += __shfl_xor(p, 1); p += __shfl_xor(p, 2);
    p += __shfl_xor(p, 4); p += __shfl_xor(p, 8);
    p *= 0.125f;                      // SCALE = 1/sqrt(64)
    float mn = fmaxf(m, p);
    float sc = expf(m - mn);
    float w  = expf(p - mn);
    den = den * sc + w;
    acc.x = acc.x * sc + w * (vv.x + ev.x);
    acc.y = acc.y * sc + w * (vv.y + ev.y);
    acc.z = acc.z * sc + w * (vv.z + ev.z);
    acc.w = acc.w * sc + w * (vv.w + ev.w);
    m = mn;
  }
  float inv = (den > 0.f) ? 1.0f / den : 0.f;
  float4 sv = *(const float4*)(s + base);
  float4 xv = *(const float4*)(x + base);
  float4 val = make_float4(xv.x + sv.x + acc.x * inv,
                           xv.y + sv.y + acc.y * inv,
                           xv.z + sv.z + acc.z * inv,
                           xv.w + sv.w + acc.w * inv);
  float t = val.x + val.y + val.z + val.w;
#pragma unroll
  for (int o = 1; o < 64; o <<= 1) t += __shfl_xor(t, o);
  float mean = t * (1.0f / 256.0f);
  float d0 = val.x - mean, d1 = val.y - mean, d2 = val.z - mean, d3 = val.w - mean;
  float ss = d0 * d0 + d1 * d1 + d2 * d2 + d3 * d3;
#pragma unroll
  for (int o = 1; o < 64; o <<= 1) ss += __shfl_xor(ss, o);
  float rstd = rsqrtf(ss * (1.0f / 256.0f) + 1e-5f);
  float4 gv = *(const float4*)(gamma + c4);
  float4 bv = *(const float4*)(beta + c4);
  float4 o4 = make_float4(d0 * rstd * gv.x + bv.x, d1 * rstd * gv.y + bv.y,
                          d2 * rstd * gv.z + bv.z, d3 * rstd * gv.w + bv.w);
  *(float4*)(out + base) = o4;
}

extern "C" void kernel_launch(void* const* d_in, const int* in_sizes, int n_in,
                              void* d_out, int out_size, void* d_ws, size_t ws_size,
                              hipStream_t stream) {
  const float* row_x   = (const float*)d_in[0];
  const float* token_x = (const float*)d_in[1];
  const int*   ei1     = (const int*)d_in[2];    // int32 (JAX x64 disabled)
  const float* ea1     = (const float*)d_in[3];
  const int*   ei2     = (const int*)d_in[4];
  const float* ea2     = (const float*)d_in[5];

  const float* W[10] = {(const float*)d_in[6],  (const float*)d_in[8],
                        (const float*)d_in[10], (const float*)d_in[12],
                        (const float*)d_in[14], (const float*)d_in[16],
                        (const float*)d_in[18], (const float*)d_in[20],
                        (const float*)d_in[22], (const float*)d_in[24]};
  const float* Bv[10] = {(const float*)d_in[7],  (const float*)d_in[9],
                         (const float*)d_in[11], (const float*)d_in[13],
                         (const float*)d_in[15], (const float*)d_in[17],
                         (const float*)d_in[19], (const float*)d_in[21],
                         (const float*)d_in[23], (const float*)d_in[25]};
  const float* row_gamma   = (const float*)d_in[26];
  const float* row_beta    = (const float*)d_in[27];
  const float* token_gamma = (const float*)d_in[28];
  const float* token_beta  = (const float*)d_in[29];

  const int NR = in_sizes[0] / 256;   // 20000
  const int NT = in_sizes[1] / 256;   // 100000
  const int E  = in_sizes[2] / 2;     // 300000

  float* out_row = (float*)d_out;
  float* out_tok = (float*)d_out + (long long)NR * 256;

  void *pq_, *pk_, *pv_, *pe_, *ps_, *pbfA_, *pbfB_, *pbfE_, *pbfW_,
       *pdeg_, *prp_, *pcur_, *pperm_, *pbs_;
  hipGetSymbolAddress(&pq_,   HIP_SYMBOL(g_q));
  hipGetSymbolAddress(&pk_,   HIP_SYMBOL(g_k));
  hipGetSymbolAddress(&pv_,   HIP_SYMBOL(g_v));
  hipGetSymbolAddress(&pe_,   HIP_SYMBOL(g_e));
  hipGetSymbolAddress(&ps_,   HIP_SYMBOL(g_s));
  hipGetSymbolAddress(&pbfA_, HIP_SYMBOL(g_bfA));
  hipGetSymbolAddress(&pbfB_, HIP_SYMBOL(g_bfB));
  hipGetSymbolAddress(&pbfE_, HIP_SYMBOL(g_bfE));
  hipGetSymbolAddress(&pbfW_, HIP_SYMBOL(g_bfW));
  hipGetSymbolAddress(&pdeg_, HIP_SYMBOL(g_deg));
  hipGetSymbolAddress(&prp_,  HIP_SYMBOL(g_rowptr));
  hipGetSymbolAddress(&pcur_, HIP_SYMBOL(g_cur));
  hipGetSymbolAddress(&pperm_,HIP_SYMBOL(g_perm));
  hipGetSymbolAddress(&pbs_,  HIP_SYMBOL(g_bsum));
  float* q    = (float*)pq_;
  float* k    = (float*)pk_;
  float* v    = (float*)pv_;
  float* e    = (float*)pe_;
  float* s    = (float*)ps_;
  unsigned short* bfA = (unsigned short*)pbfA_;   // token_x bf16
  unsigned short* bfB = (unsigned short*)pbfB_;   // row_x / out_row bf16
  unsigned short* bfE = (unsigned short*)pbfE_;   // edge attr bf16
  unsigned short* bfW = (unsigned short*)pbfW_;
  int*   deg  = (int*)pdeg_;
  int*   rp   = (int*)prp_;
  int*   cur  = (int*)pcur_;
  int*   perm = (int*)pperm_;
  int*   bsum = (int*)pbs_;

  auto Wt = [&](int i) { return bfW + (size_t)i * 65536; };

  // Weight transpose-converts (q,k,v,e,s x 2 phases); e has K=128.
  for (int i = 0; i < 10; ++i) {
    int K = (i % 5 == 3) ? 128 : 256;
    wconv<<<(K * 256 + 255) / 256, 256, 0, stream>>>(W[i], Wt(i), K);
  }
  // Activation converts for phase 1.
  conv_bf16<<<(int)(((long long)NT * 32 + 255) / 256), 256, 0, stream>>>(token_x, bfA, (long long)NT * 32);
  conv_bf16<<<(int)(((long long)NR * 32 + 255) / 256), 256, 0, stream>>>(row_x, bfB, (long long)NR * 32);
  conv_bf16<<<(int)(((long long)E * 16 + 255) / 256), 256, 0, stream>>>(ea1, bfE, (long long)E * 16);

  auto g256 = [&](const unsigned short* A, int wi, float* C, int M) {
    dim3 grid((M + 127) / 128, 2);
    gemm_mfma<256><<<grid, 256, 0, stream>>>(A, Wt(wi), Bv[wi], C, M);
  };
  auto g128 = [&](const unsigned short* A, int wi, float* C, int M) {
    dim3 grid((M + 127) / 128, 2);
    gemm_mfma<128><<<grid, 256, 0, stream>>>(A, Wt(wi), Bv[wi], C, M);
  };

  const int egrid = (E + 255) / 256;

  auto run_phase = [&](const unsigned short* xs_bf, const unsigned short* xd_bf,
                       const float* x_dst, const int* ei, int wbase,
                       const float* gamma, const float* beta,
                       float* outp, int Ndst, int Nsrc) {
    g256(xd_bf, wbase + 0, q, Ndst);
    g256(xs_bf, wbase + 1, k, Nsrc);
    g256(xs_bf, wbase + 2, v, Nsrc);
    g128(bfE,   wbase + 3, e, E);
    g256(xd_bf, wbase + 4, s, Ndst);
    hipMemsetAsync(deg, 0, (size_t)(Ndst + 1) * sizeof(int), stream);
    hist_kernel<<<egrid, 256, 0, stream>>>(ei, deg, E);
    int B = (Ndst + 255) / 256;
    scan1<<<B, 256, 0, stream>>>(deg, rp, bsum, Ndst);
    scan2<<<1, 512, 0, stream>>>(bsum, B);
    scan3<<<B, 256, 0, stream>>>(rp, bsum, deg, cur, Ndst);
    scatter_kernel<<<egrid, 256, 0, stream>>>(ei, cur, perm, E);
    fused_attn_ln<<<(Ndst + 3) / 4, 256, 0, stream>>>(ei, rp, perm, q, k, v, e,
                                                      x_dst, s, gamma, beta,
                                                      outp, Ndst, E);
  };

  // Phase 1: t2r (src=token_x, dst=row_x)
  run_phase(bfA, bfB, row_x, ei1, 0, row_gamma, row_beta, out_row, NR, NT);

  // Convert out_row and ea2 for phase 2.
  conv_bf16<<<(int)(((long long)NR * 32 + 255) / 256), 256, 0, stream>>>(out_row, bfB, (long long)NR * 32);
  conv_bf16<<<(int)(((long long)E * 16 + 255) / 256), 256, 0, stream>>>(ea2, bfE, (long long)E * 16);

  // Phase 2: r2t (src=out_row, dst=token_x)
  run_phase(bfB, bfA, token_x, ei2, 5, token_gamma, token_beta, out_tok, NT, NR);
}

// Round 5
// 736.310 us; speedup vs baseline: 5.5382x; 2.0242x over previous
//
#include <hip/hip_runtime.h>
#include <cstdint>
#include <cstddef>

#define NMAX 100000
#define EMAX 300000

typedef __bf16 bf16x8 __attribute__((ext_vector_type(8)));
typedef float f32x4 __attribute__((ext_vector_type(4)));

// Static device scratch (fully rewritten every launch).
__device__ unsigned short g_qs [(size_t)NMAX * 512];   // [q | s] bf16
__device__ unsigned short g_kv [(size_t)NMAX * 512];   // [k | v] bf16
__device__ unsigned short g_eb [(size_t)EMAX * 256];   // e-proj bf16
__device__ unsigned short g_bfA[(size_t)NMAX * 256];   // token_x bf16
__device__ unsigned short g_bfB[(size_t)NMAX * 256];   // row_x bf16 -> out_row bf16
__device__ unsigned short g_bfE[(size_t)EMAX * 128];   // edge_attr bf16
__device__ unsigned short g_bfW[589824];               // transposed bf16 weights
__device__ float g_bias[2560];                          // concat biases
__device__ int   g_deg [NMAX + 1];
__device__ int   g_rowptr[NMAX + 1];
__device__ int   g_cur [NMAX];
__device__ int   g_perm[EMAX];
__device__ int   g_bsum[512];

struct P10 { const float* p[10]; };

__device__ __forceinline__ unsigned short f2bf(float f) {
  unsigned u = __float_as_uint(f);
  return (unsigned short)((u + 0x7fffu + ((u >> 16) & 1u)) >> 16);
}
__device__ __forceinline__ float bf2f(unsigned short h) {
  return __uint_as_float((unsigned)h << 16);
}

// f32 -> bf16, 8 elems/thread.
__global__ __launch_bounds__(256) void conv_bf16(const float* __restrict__ in,
                                                 unsigned short* __restrict__ out,
                                                 long long n8) {
  long long i = (long long)blockIdx.x * 256 + threadIdx.x;
  if (i >= n8) return;
  const float4* p = (const float4*)(in + i * 8);
  float4 a = p[0], b = p[1];
  ushort4 lo = make_ushort4(f2bf(a.x), f2bf(a.y), f2bf(a.z), f2bf(a.w));
  ushort4 hi = make_ushort4(f2bf(b.x), f2bf(b.y), f2bf(b.z), f2bf(b.w));
  ushort4* q = (ushort4*)(out + i * 8);
  q[0] = lo; q[1] = hi;
}

// [W0|W1] (each [K,256] f32) -> Wt[NN,K] bf16 transposed; NN=512 or 256.
__global__ __launch_bounds__(256) void wconv2(const float* __restrict__ W0,
                                              const float* __restrict__ W1,
                                              unsigned short* __restrict__ Wt,
                                              int K, int NN) {
  int i = blockIdx.x * 256 + threadIdx.x;
  if (i >= NN * K) return;
  int n = i / K, k = i - n * K;
  const float* W = (n < 256) ? W0 : W1;
  Wt[i] = f2bf(W[(size_t)k * 256 + (n & 255)]);
}

// Concatenate 10 bias vectors (256 each) into g_bias.
__global__ __launch_bounds__(256) void bconcat(P10 b, float* __restrict__ out) {
  int i = blockIdx.x * 256 + threadIdx.x;
  if (i < 2560) out[i] = b.p[i >> 8][i & 255];
}

#define GLL16(gp, lp) __builtin_amdgcn_global_load_lds( \
    (const __attribute__((address_space(1))) void*)(gp), \
    (__attribute__((address_space(3))) void*)(lp), 16, 0, 0)

// C[M,NS](bf16) = bf16(A[M,K]) @ Wt^T + bias ; 128x128 tile, BK=64, 4 waves,
// 16x16x32 bf16 MFMA, global_load_lds + XOR swizzle both sides.
template <int K, int NS>
__global__ __launch_bounds__(256) void gemm_mfma(const unsigned short* __restrict__ A,
                                                 const unsigned short* __restrict__ Bt,
                                                 const float* __restrict__ bias,
                                                 unsigned short* __restrict__ C, int M) {
  __shared__ unsigned short As[128 * 64];
  __shared__ unsigned short Bs[128 * 64];
  const int tid = threadIdx.x;
  const int lane = tid & 63, wid = tid >> 6;
  const int bm = blockIdx.x * 128, bn = blockIdx.y * 128;
  const int wrow = (wid & 1) * 64, wcol = (wid >> 1) * 64;
  const int sr = lane >> 3;
  const int slot = lane & 7;

  f32x4 acc[4][4] = {};

  for (int k0 = 0; k0 < K; k0 += 64) {
#pragma unroll
    for (int r = 0; r < 4; ++r) {
      int row = (wid * 4 + r) * 8 + sr;
      int arow = bm + row; if (arow >= M) arow = M - 1;
      int kk = k0 + ((slot ^ (row & 7)) << 3);
      GLL16(A + (size_t)arow * K + kk, (unsigned short*)As + (size_t)(wid * 4 + r) * 512);
    }
#pragma unroll
    for (int r = 0; r < 4; ++r) {
      int col = (wid * 4 + r) * 8 + sr;
      int kk = k0 + ((slot ^ (col & 7)) << 3);
      GLL16(Bt + (size_t)(bn + col) * K + kk, (unsigned short*)Bs + (size_t)(wid * 4 + r) * 512);
    }
    __syncthreads();
    const char* Ab = (const char*)As;
    const char* Bb = (const char*)Bs;
#pragma unroll
    for (int h = 0; h < 2; ++h) {
      bf16x8 af[4], bfr[4];
      int g = (lane >> 4) + h * 4;
#pragma unroll
      for (int fm = 0; fm < 4; ++fm) {
        int row = wrow + fm * 16 + (lane & 15);
        af[fm] = *(const bf16x8*)(Ab + row * 128 + ((g ^ (row & 7)) << 4));
      }
#pragma unroll
      for (int fn = 0; fn < 4; ++fn) {
        int col = wcol + fn * 16 + (lane & 15);
        bfr[fn] = *(const bf16x8*)(Bb + col * 128 + ((g ^ (col & 7)) << 4));
      }
#pragma unroll
      for (int fm = 0; fm < 4; ++fm)
#pragma unroll
        for (int fn = 0; fn < 4; ++fn)
          acc[fm][fn] = __builtin_amdgcn_mfma_f32_16x16x32_bf16(af[fm], bfr[fn],
                                                                acc[fm][fn], 0, 0, 0);
    }
    __syncthreads();
  }
  // Epilogue: bias + bf16 store, fn innermost for write locality.
  float bv[4];
#pragma unroll
  for (int fn = 0; fn < 4; ++fn) bv[fn] = bias[bn + wcol + fn * 16 + (lane & 15)];
#pragma unroll
  for (int fm = 0; fm < 4; ++fm) {
    int rbase = bm + wrow + fm * 16 + ((lane >> 4) << 2);
#pragma unroll
    for (int j = 0; j < 4; ++j) {
      int row = rbase + j;
      if (row < M) {
        size_t rb = (size_t)row * NS + bn + wcol + (lane & 15);
#pragma unroll
        for (int fn = 0; fn < 4; ++fn)
          C[rb + fn * 16] = f2bf(acc[fm][fn][j] + bv[fn]);
      }
    }
  }
}

// ---------------- CSR build ----------------
__global__ __launch_bounds__(256) void hist_kernel(const int* __restrict__ ei,
                                                   int* __restrict__ deg, int E) {
  int i = blockIdx.x * 256 + threadIdx.x;
  if (i < E) atomicAdd(&deg[ei[E + i]], 1);
}

__global__ __launch_bounds__(256) void scan1(const int* __restrict__ deg,
                                             int* __restrict__ rowptr,
                                             int* __restrict__ bsum, int n) {
  __shared__ int ws[4];
  int i = blockIdx.x * 256 + threadIdx.x;
  int v = (i < n) ? deg[i] : 0;
  int lane = threadIdx.x & 63, wid = threadIdx.x >> 6;
  int inc = v;
#pragma unroll
  for (int o = 1; o < 64; o <<= 1) {
    int t = __shfl_up(inc, o);
    if (lane >= o) inc += t;
  }
  if (lane == 63) ws[wid] = inc;
  __syncthreads();
  int woff = 0;
  if (wid > 0) woff += ws[0];
  if (wid > 1) woff += ws[1];
  if (wid > 2) woff += ws[2];
  if (i < n) rowptr[i] = inc - v + woff;
  if (threadIdx.x == 255) bsum[blockIdx.x] = inc + woff;
}

__global__ __launch_bounds__(512) void scan2(int* __restrict__ bsum, int B) {
  __shared__ int s[512];
  int t = threadIdx.x;
  int v = (t < B) ? bsum[t] : 0;
  s[t] = v;
  __syncthreads();
  for (int o = 1; o < 512; o <<= 1) {
    int a = (t >= o) ? s[t - o] : 0;
    __syncthreads();
    s[t] += a;
    __syncthreads();
  }
  if (t < B) bsum[t] = s[t] - v;
}

__global__ __launch_bounds__(256) void scan3(int* __restrict__ rowptr,
                                             const int* __restrict__ bsum,
                                             const int* __restrict__ deg,
                                             int* __restrict__ cur, int n) {
  int i = blockIdx.x * 256 + threadIdx.x;
  if (i < n) {
    int r = rowptr[i] + bsum[blockIdx.x];
    rowptr[i] = r;
    cur[i] = r;
    if (i == n - 1) rowptr[n] = r + deg[i];
  }
}

__global__ __launch_bounds__(256) void scatter_kernel(const int* __restrict__ ei,
                                                      int* __restrict__ cur,
                                                      int* __restrict__ perm, int E) {
  int i = blockIdx.x * 256 + threadIdx.x;
  if (i < E) {
    int d = ei[E + i];
    int pos = atomicAdd(&cur[d], 1);
    perm[pos] = i;
  }
}

// ---------------- Fused attention + skip + residual + LN (bf16 streams) ---
__global__ __launch_bounds__(256) void fused_attn_ln(
    const int* __restrict__ ei, const int* __restrict__ rowptr,
    const int* __restrict__ perm,
    const unsigned short* __restrict__ qs, const unsigned short* __restrict__ kv,
    const unsigned short* __restrict__ eb,
    const float* __restrict__ x,
    const float* __restrict__ gamma, const float* __restrict__ beta,
    float* __restrict__ out, unsigned short* __restrict__ out_bf, int N, int E) {
  int node = blockIdx.x * 4 + (threadIdx.x >> 6);
  if (node >= N) return;
  int lane = threadIdx.x & 63;
  int c4 = lane << 2;
  ushort4 qu = *(const ushort4*)(qs + (size_t)node * 512 + c4);
  float4 qv = make_float4(bf2f(qu.x), bf2f(qu.y), bf2f(qu.z), bf2f(qu.w));
  float4 acc = make_float4(0.f, 0.f, 0.f, 0.f);
  float m = -1e30f, den = 0.f;
  int beg = rowptr[node], end = rowptr[node + 1];
  for (int p_ = beg; p_ < end; ++p_) {
    int eid = perm[p_];
    size_t src = (size_t)ei[eid];
    ushort4 ku = *(const ushort4*)(kv + src * 512 + c4);
    ushort4 vu = *(const ushort4*)(kv + src * 512 + 256 + c4);
    ushort4 eu = *(const ushort4*)(eb + (size_t)eid * 256 + c4);
    float e0 = bf2f(eu.x), e1 = bf2f(eu.y), e2 = bf2f(eu.z), e3 = bf2f(eu.w);
    float p = qv.x * (bf2f(ku.x) + e0) + qv.y * (bf2f(ku.y) + e1) +
              qv.z * (bf2f(ku.z) + e2) + qv.w * (bf2f(ku.w) + e3);
    p += __shfl_xor(p, 1); p += __shfl_xor(p, 2);
    p += __shfl_xor(p, 4); p += __shfl_xor(p, 8);
    p *= 0.125f;                      // SCALE = 1/sqrt(64)
    float mn = fmaxf(m, p);
    float sc = expf(m - mn);
    float w  = expf(p - mn);
    den = den * sc + w;
    acc.x = acc.x * sc + w * (bf2f(vu.x) + e0);
    acc.y = acc.y * sc + w * (bf2f(vu.y) + e1);
    acc.z = acc.z * sc + w * (bf2f(vu.z) + e2);
    acc.w = acc.w * sc + w * (bf2f(vu.w) + e3);
    m = mn;
  }
  float inv = (den > 0.f) ? 1.0f / den : 0.f;
  ushort4 su = *(const ushort4*)(qs + (size_t)node * 512 + 256 + c4);
  size_t base = (size_t)node * 256 + c4;
  float4 xv = *(const float4*)(x + base);
  float4 val = make_float4(xv.x + bf2f(su.x) + acc.x * inv,
                           xv.y + bf2f(su.y) + acc.y * inv,
                           xv.z + bf2f(su.z) + acc.z * inv,
                           xv.w + bf2f(su.w) + acc.w * inv);
  float t = val.x + val.y + val.z + val.w;
#pragma unroll
  for (int o = 1; o < 64; o <<= 1) t += __shfl_xor(t, o);
  float mean = t * (1.0f / 256.0f);
  float d0 = val.x - mean, d1 = val.y - mean, d2 = val.z - mean, d3 = val.w - mean;
  float ss = d0 * d0 + d1 * d1 + d2 * d2 + d3 * d3;
#pragma unroll
  for (int o = 1; o < 64; o <<= 1) ss += __shfl_xor(ss, o);
  float rstd = rsqrtf(ss * (1.0f / 256.0f) + 1e-5f);
  float4 gv = *(const float4*)(gamma + c4);
  float4 bv = *(const float4*)(beta + c4);
  float4 o4 = make_float4(d0 * rstd * gv.x + bv.x, d1 * rstd * gv.y + bv.y,
                          d2 * rstd * gv.z + bv.z, d3 * rstd * gv.w + bv.w);
  *(float4*)(out + base) = o4;
  if (out_bf) {
    ushort4 ob = make_ushort4(f2bf(o4.x), f2bf(o4.y), f2bf(o4.z), f2bf(o4.w));
    *(ushort4*)(out_bf + base) = ob;
  }
}

extern "C" void kernel_launch(void* const* d_in, const int* in_sizes, int n_in,
                              void* d_out, int out_size, void* d_ws, size_t ws_size,
                              hipStream_t stream) {
  const float* row_x   = (const float*)d_in[0];
  const float* token_x = (const float*)d_in[1];
  const int*   ei1     = (const int*)d_in[2];    // int32 (JAX x64 disabled)
  const float* ea1     = (const float*)d_in[3];
  const int*   ei2     = (const int*)d_in[4];
  const float* ea2     = (const float*)d_in[5];

  // per phase: Wq,bq,Wk,bk,Wv,bv,We,be,Ws,bs
  const float* W1q = (const float*)d_in[6];  const float* b1q = (const float*)d_in[7];
  const float* W1k = (const float*)d_in[8];  const float* b1k = (const float*)d_in[9];
  const float* W1v = (const float*)d_in[10]; const float* b1v = (const float*)d_in[11];
  const float* W1e = (const float*)d_in[12]; const float* b1e = (const float*)d_in[13];
  const float* W1s = (const float*)d_in[14]; const float* b1s = (const float*)d_in[15];
  const float* W2q = (const float*)d_in[16]; const float* b2q = (const float*)d_in[17];
  const float* W2k = (const float*)d_in[18]; const float* b2k = (const float*)d_in[19];
  const float* W2v = (const float*)d_in[20]; const float* b2v = (const float*)d_in[21];
  const float* W2e = (const float*)d_in[22]; const float* b2e = (const float*)d_in[23];
  const float* W2s = (const float*)d_in[24]; const float* b2s = (const float*)d_in[25];
  const float* row_gamma   = (const float*)d_in[26];
  const float* row_beta    = (const float*)d_in[27];
  const float* token_gamma = (const float*)d_in[28];
  const float* token_beta  = (const float*)d_in[29];

  const int NR = in_sizes[0] / 256;   // 20000
  const int NT = in_sizes[1] / 256;   // 100000
  const int E  = in_sizes[2] / 2;     // 300000

  float* out_row = (float*)d_out;
  float* out_tok = (float*)d_out + (long long)NR * 256;

  void *pqs_, *pkv_, *peb_, *pbfA_, *pbfB_, *pbfE_, *pbfW_, *pbias_,
       *pdeg_, *prp_, *pcur_, *pperm_, *pbs_;
  hipGetSymbolAddress(&pqs_,  HIP_SYMBOL(g_qs));
  hipGetSymbolAddress(&pkv_,  HIP_SYMBOL(g_kv));
  hipGetSymbolAddress(&peb_,  HIP_SYMBOL(g_eb));
  hipGetSymbolAddress(&pbfA_, HIP_SYMBOL(g_bfA));
  hipGetSymbolAddress(&pbfB_, HIP_SYMBOL(g_bfB));
  hipGetSymbolAddress(&pbfE_, HIP_SYMBOL(g_bfE));
  hipGetSymbolAddress(&pbfW_, HIP_SYMBOL(g_bfW));
  hipGetSymbolAddress(&pbias_,HIP_SYMBOL(g_bias));
  hipGetSymbolAddress(&pdeg_, HIP_SYMBOL(g_deg));
  hipGetSymbolAddress(&prp_,  HIP_SYMBOL(g_rowptr));
  hipGetSymbolAddress(&pcur_, HIP_SYMBOL(g_cur));
  hipGetSymbolAddress(&pperm_,HIP_SYMBOL(g_perm));
  hipGetSymbolAddress(&pbs_,  HIP_SYMBOL(g_bsum));
  unsigned short* qs  = (unsigned short*)pqs_;
  unsigned short* kv  = (unsigned short*)pkv_;
  unsigned short* eb  = (unsigned short*)peb_;
  unsigned short* bfA = (unsigned short*)pbfA_;
  unsigned short* bfB = (unsigned short*)pbfB_;
  unsigned short* bfE = (unsigned short*)pbfE_;
  unsigned short* bfW = (unsigned short*)pbfW_;
  float* gbias = (float*)pbias_;
  int*   deg  = (int*)pdeg_;
  int*   rp   = (int*)prp_;
  int*   cur  = (int*)pcur_;
  int*   perm = (int*)pperm_;
  int*   bsum = (int*)pbs_;

  // Weight layout in g_bfW (elements): qs1@0, kv1@131072, e1@262144,
  // qs2@294912, kv2@425984, e2@557056.
  unsigned short* Wqs1 = bfW + 0;
  unsigned short* Wkv1 = bfW + 131072;
  unsigned short* We1  = bfW + 262144;
  unsigned short* Wqs2 = bfW + 294912;
  unsigned short* Wkv2 = bfW + 425984;
  unsigned short* We2  = bfW + 557056;
  wconv2<<<512, 256, 0, stream>>>(W1q, W1s, Wqs1, 256, 512);
  wconv2<<<512, 256, 0, stream>>>(W1k, W1v, Wkv1, 256, 512);
  wconv2<<<128, 256, 0, stream>>>(W1e, nullptr, We1, 128, 256);
  wconv2<<<512, 256, 0, stream>>>(W2q, W2s, Wqs2, 256, 512);
  wconv2<<<512, 256, 0, stream>>>(W2k, W2v, Wkv2, 256, 512);
  wconv2<<<128, 256, 0, stream>>>(W2e, nullptr, We2, 128, 256);
  // Bias layout: [b1q|b1s]@0, [b1k|b1v]@512, b1e@1024, [b2q|b2s]@1280,
  // [b2k|b2v]@1792, b2e@2304.
  P10 bp{{b1q, b1s, b1k, b1v, b1e, b2q, b2s, b2k, b2v, b2e}};
  bconcat<<<10, 256, 0, stream>>>(bp, gbias);

  conv_bf16<<<(int)(((long long)NT * 32 + 255) / 256), 256, 0, stream>>>(token_x, bfA, (long long)NT * 32);
  conv_bf16<<<(int)(((long long)NR * 32 + 255) / 256), 256, 0, stream>>>(row_x, bfB, (long long)NR * 32);
  conv_bf16<<<(int)(((long long)E * 16 + 255) / 256), 256, 0, stream>>>(ea1, bfE, (long long)E * 16);

  const int egrid = (E + 255) / 256;

  auto csr = [&](const int* ei, int Ndst) {
    hipMemsetAsync(deg, 0, (size_t)(Ndst + 1) * sizeof(int), stream);
    hist_kernel<<<egrid, 256, 0, stream>>>(ei, deg, E);
    int B = (Ndst + 255) / 256;
    scan1<<<B, 256, 0, stream>>>(deg, rp, bsum, Ndst);
    scan2<<<1, 512, 0, stream>>>(bsum, B);
    scan3<<<B, 256, 0, stream>>>(rp, bsum, deg, cur, Ndst);
    scatter_kernel<<<egrid, 256, 0, stream>>>(ei, cur, perm, E);
  };

  // ---------------- Phase 1: t2r ----------------
  {
    dim3 gqs((NR + 127) / 128, 4), gkv((NT + 127) / 128, 4), ge((E + 127) / 128, 2);
    gemm_mfma<256, 512><<<gqs, 256, 0, stream>>>(bfB, Wqs1, gbias + 0,    qs, NR);
    gemm_mfma<256, 512><<<gkv, 256, 0, stream>>>(bfA, Wkv1, gbias + 512,  kv, NT);
    gemm_mfma<128, 256><<<ge,  256, 0, stream>>>(bfE, We1,  gbias + 1024, eb, E);
    csr(ei1, NR);
    fused_attn_ln<<<(NR + 3) / 4, 256, 0, stream>>>(ei1, rp, perm, qs, kv, eb,
                                                    row_x, row_gamma, row_beta,
                                                    out_row, bfB, NR, E);
  }

  conv_bf16<<<(int)(((long long)E * 16 + 255) / 256), 256, 0, stream>>>(ea2, bfE, (long long)E * 16);

  // ---------------- Phase 2: r2t ----------------
  {
    dim3 gqs((NT + 127) / 128, 4), gkv((NR + 127) / 128, 4), ge((E + 127) / 128, 2);
    gemm_mfma<256, 512><<<gqs, 256, 0, stream>>>(bfA, Wqs2, gbias + 1280, qs, NT);
    gemm_mfma<256, 512><<<gkv, 256, 0, stream>>>(bfB, Wkv2, gbias + 1792, kv, NR);
    gemm_mfma<128, 256><<<ge,  256, 0, stream>>>(bfE, We2,  gbias + 2304, eb, E);
    csr(ei2, NT);
    fused_attn_ln<<<(NT + 3) / 4, 256, 0, stream>>>(ei2, rp, perm, qs, kv, eb,
                                                    token_x, token_gamma, token_beta,
                                                    out_tok, nullptr, NT, E);
  }
}